// Round 2
// baseline (270.543 us; speedup 1.0000x reference)
//
#include <hip/hip_runtime.h>

// SerializedEmbedding: out[b,s,:] = weight[indices[b,s], :]
// indices: 16384 int32 tokens, weight: (50304, 1024) fp32, out: (16384, 1024) fp32
//
// Structure: 4 waves/block, each WAVE owns TOKENS_PER_WAVE=4 tokens.
//  - one int4 broadcast load fetches the wave's 4 indices
//  - each lane issues 16 independent global_load_dwordx4 (4 rows x 4 f4/lane)
//    before any store -> deep MLP, hides HBM gather latency
//  - nontemporal stores for the streaming output (no reuse; keep L2 for weight rows)
// Grid: 1024 blocks (16 tokens/block) instead of 16384 tiny blocks.

#define EMB_DIM 1024
#define F4_PER_ROW (EMB_DIM / 4)      // 256 float4 per row
#define TOKENS_PER_WAVE 4
#define WAVES_PER_BLOCK 4
#define BLOCK_THREADS 256
#define TOKENS_PER_BLOCK (TOKENS_PER_WAVE * WAVES_PER_BLOCK)  // 16

// native clang vector type (NOT HIP_vector_type) so __builtin_nontemporal_store accepts it
typedef float f32x4 __attribute__((ext_vector_type(4)));
typedef int   i32x4 __attribute__((ext_vector_type(4)));

__global__ __launch_bounds__(BLOCK_THREADS) void SerializedEmbedding_7121055777167_kernel(
    const int* __restrict__ indices,
    const float* __restrict__ weight,
    float* __restrict__ out,
    int num_tokens)
{
    const int wave = threadIdx.x >> 6;     // 0..3
    const int lane = threadIdx.x & 63;     // 0..63

    const int t0 = (blockIdx.x * WAVES_PER_BLOCK + wave) * TOKENS_PER_WAVE;
    if (t0 >= num_tokens) return;

    const f32x4* __restrict__ w4 = reinterpret_cast<const f32x4*>(weight);
    f32x4* __restrict__ o4       = reinterpret_cast<f32x4*>(out);

    if (t0 + TOKENS_PER_WAVE <= num_tokens) {
        // --- fast path: 4 tokens per wave ---
        // all 64 lanes read the same 16B -> one cache-line broadcast
        const i32x4 idx4 = *reinterpret_cast<const i32x4*>(indices + t0);

        const size_t r0 = (size_t)idx4.x * F4_PER_ROW;
        const size_t r1 = (size_t)idx4.y * F4_PER_ROW;
        const size_t r2 = (size_t)idx4.z * F4_PER_ROW;
        const size_t r3 = (size_t)idx4.w * F4_PER_ROW;

        f32x4 v[TOKENS_PER_WAVE][4];
        #pragma unroll
        for (int k = 0; k < 4; ++k) {
            v[0][k] = w4[r0 + lane + k * 64];
            v[1][k] = w4[r1 + lane + k * 64];
            v[2][k] = w4[r2 + lane + k * 64];
            v[3][k] = w4[r3 + lane + k * 64];
        }

        #pragma unroll
        for (int t = 0; t < TOKENS_PER_WAVE; ++t) {
            const size_t ob = (size_t)(t0 + t) * F4_PER_ROW;
            #pragma unroll
            for (int k = 0; k < 4; ++k) {
                __builtin_nontemporal_store(v[t][k], &o4[ob + lane + k * 64]);
            }
        }
    } else {
        // --- tail path: per-token copy ---
        for (int t = t0; t < num_tokens; ++t) {
            const size_t rb = (size_t)indices[t] * F4_PER_ROW;
            const size_t ob = (size_t)t * F4_PER_ROW;
            #pragma unroll
            for (int k = 0; k < 4; ++k) {
                __builtin_nontemporal_store(w4[rb + lane + k * 64],
                                            &o4[ob + lane + k * 64]);
            }
        }
    }
}

extern "C" void kernel_launch(void* const* d_in, const int* in_sizes, int n_in,
                              void* d_out, int out_size, void* d_ws, size_t ws_size,
                              hipStream_t stream)
{
    const int*   indices = (const int*)d_in[0];
    const float* weight  = (const float*)d_in[1];
    float*       out     = (float*)d_out;

    const int num_tokens = in_sizes[0];  // 8 * 2048 = 16384

    const int grid = (num_tokens + TOKENS_PER_BLOCK - 1) / TOKENS_PER_BLOCK;  // 1024

    SerializedEmbedding_7121055777167_kernel<<<dim3(grid), dim3(BLOCK_THREADS), 0, stream>>>(
        indices, weight, out, num_tokens);
}